// Round 1
// baseline (392.790 us; speedup 1.0000x reference)
//
#include <hip/hip_runtime.h>

#define D 100
#define HALF_D 50

// ---------------- CSR build ----------------

__global__ __launch_bounds__(256) void k_hist(const int* __restrict__ dst, int* __restrict__ cnt, int E) {
    int e = blockIdx.x * 256 + threadIdx.x;
    if (e < E) atomicAdd(&cnt[dst[e]], 1);
}

__global__ __launch_bounds__(256) void k_blocksum(const int* __restrict__ cnt, int* __restrict__ bsum, int n) {
    __shared__ int s[256];
    int i = blockIdx.x * 256 + threadIdx.x;
    s[threadIdx.x] = (i < n) ? cnt[i] : 0;
    __syncthreads();
    for (int off = 128; off; off >>= 1) {
        if (threadIdx.x < off) s[threadIdx.x] += s[threadIdx.x + off];
        __syncthreads();
    }
    if (threadIdx.x == 0) bsum[blockIdx.x] = s[0];
}

// single block: exclusive scan of nb (<=256) block sums
__global__ __launch_bounds__(256) void k_scan_bsum(const int* __restrict__ bsum, int* __restrict__ boff, int nb) {
    __shared__ int s[256];
    int v = (threadIdx.x < nb) ? bsum[threadIdx.x] : 0;
    s[threadIdx.x] = v;
    __syncthreads();
    for (int off = 1; off < 256; off <<= 1) {
        int t = (threadIdx.x >= off) ? s[threadIdx.x - off] : 0;
        __syncthreads();
        s[threadIdx.x] += t;
        __syncthreads();
    }
    if (threadIdx.x < nb) boff[threadIdx.x] = s[threadIdx.x] - v;  // exclusive
}

__global__ __launch_bounds__(256) void k_scan_write(const int* __restrict__ cnt, const int* __restrict__ boff,
                                                    int* __restrict__ rowptr, int n, int E) {
    __shared__ int s[256];
    int i = blockIdx.x * 256 + threadIdx.x;
    int v = (i < n) ? cnt[i] : 0;
    s[threadIdx.x] = v;
    __syncthreads();
    for (int off = 1; off < 256; off <<= 1) {
        int t = (threadIdx.x >= off) ? s[threadIdx.x - off] : 0;
        __syncthreads();
        s[threadIdx.x] += t;
        __syncthreads();
    }
    if (i < n) rowptr[i] = boff[blockIdx.x] + s[threadIdx.x] - v;
    if (blockIdx.x == 0 && threadIdx.x == 0) rowptr[n] = E;
}

__global__ __launch_bounds__(256) void k_fill(const int* __restrict__ src, const int* __restrict__ dst,
                                              const int* __restrict__ rowptr, int* __restrict__ cur,
                                              int* __restrict__ col, int E) {
    int e = blockIdx.x * 256 + threadIdx.x;
    if (e >= E) return;
    int d = dst[e];
    int pos = rowptr[d] + atomicAdd(&cur[d], 1);
    col[pos] = src[e];
}

// ---------------- GEMM: y = x @ W^T  (W is [D][D], y[r][c] = sum_k x[r][k]*W[c][k]) ----------------
// W^T staged in LDS; 2 threads per row, each owns 50 accumulators.
__global__ __launch_bounds__(256) void k_gemm(const float* __restrict__ x, const float* __restrict__ W,
                                              float* __restrict__ y, int N) {
    __shared__ float WT[D][D];  // WT[k][c] = W[c][k], 40 KB
    for (int i = threadIdx.x; i < D * D; i += 256) {
        int c = i / D, k = i - c * D;
        WT[k][c] = W[i];
    }
    __syncthreads();
    int tid  = blockIdx.x * 256 + threadIdx.x;
    int r    = tid >> 1;
    int half = tid & 1;
    if (r >= N) return;

    float acc[HALF_D];
#pragma unroll
    for (int c = 0; c < HALF_D; c++) acc[c] = 0.f;

    const float4* xr    = (const float4*)(x + (long)r * D);
    const float*  wbase = &WT[0][half * HALF_D];
#pragma unroll 1
    for (int k4 = 0; k4 < D / 4; k4++) {
        float4 xv = xr[k4];
#pragma unroll
        for (int j = 0; j < 4; j++) {
            float xs = (j == 0) ? xv.x : (j == 1) ? xv.y : (j == 2) ? xv.z : xv.w;
            const float* wk = wbase + (k4 * 4 + j) * D;
#pragma unroll
            for (int c = 0; c < HALF_D; c++) acc[c] += xs * wk[c];
        }
    }
    float* yr = y + (long)r * D + half * HALF_D;
#pragma unroll
    for (int c = 0; c < HALF_D; c += 2) {
        *(float2*)(yr + c) = make_float2(acc[c], acc[c + 1]);
    }
}

// ---------------- fused SpMM + row-normalize + avg update ----------------
// One wave per node. Lanes 0..49 each own float2 (dims 2*lane, 2*lane+1).
// x_new[d] = (1/deg) * (y[d] + sum_{e in row d} y[col[e]])
// avg[d]   = basein[d]*basescale + (x_new[d]/max(||x_new[d]||,1e-12)) * invlp1
__global__ __launch_bounds__(256) void k_spmm(const float* __restrict__ y, const int* __restrict__ rowptr,
                                              const int* __restrict__ col, const float* __restrict__ basein,
                                              float basescale, float invlp1,
                                              float* __restrict__ xnew, float* __restrict__ avg, int N) {
    int wave = threadIdx.x >> 6;
    int lane = threadIdx.x & 63;
    int d = blockIdx.x * 4 + wave;
    if (d >= N) return;

    int beg = rowptr[d], end = rowptr[d + 1];
    bool act = lane < HALF_D;

    float2 acc = make_float2(0.f, 0.f);
    if (act) {  // self loop
        float2 v = *(const float2*)(y + (long)d * D + lane * 2);
        acc = v;
    }
    for (int base = beg; base < end; base += 64) {
        int m = min(64, end - base);
        int c = (lane < m) ? col[base + lane] : 0;
        for (int j = 0; j < m; j++) {
            int s = __shfl(c, j);
            if (act) {
                float2 v = *(const float2*)(y + (long)s * D + lane * 2);
                acc.x += v.x;
                acc.y += v.y;
            }
        }
    }
    float dinv = 1.f / (float)(end - beg + 1);
    acc.x *= dinv;
    acc.y *= dinv;

    float nsq = act ? (acc.x * acc.x + acc.y * acc.y) : 0.f;
    for (int off = 32; off; off >>= 1) nsq += __shfl_xor(nsq, off);
    float scale = invlp1 / fmaxf(sqrtf(nsq), 1e-12f);

    if (act) {
        *(float2*)(xnew + (long)d * D + lane * 2) = acc;
        float2 b = *(const float2*)(basein + (long)d * D + lane * 2);
        float2 o;
        o.x = b.x * basescale + acc.x * scale;
        o.y = b.y * basescale + acc.y * scale;
        *(float2*)(avg + (long)d * D + lane * 2) = o;
    }
}

// ---------------- launcher ----------------

extern "C" void kernel_launch(void* const* d_in, const int* in_sizes, int n_in,
                              void* d_out, int out_size, void* d_ws, size_t ws_size,
                              hipStream_t stream) {
    const float* features = (const float*)d_in[0];
    const float* W        = (const float*)d_in[1];
    const int*   src      = (const int*)d_in[2];
    const int*   dstv     = (const int*)d_in[3];

    int N = in_sizes[0] / D;            // 50000
    int E = in_sizes[2];                // 800000
    int L = in_sizes[1] / (D * D);      // 2
    float invlp1 = 1.f / (float)(L + 1);

    char*  ws  = (char*)d_ws;
    size_t off = 0;
    auto alloc = [&](size_t bytes) -> void* {
        void* p = (void*)(ws + off);
        off += (bytes + 255) & ~(size_t)255;
        return p;
    };
    float* y      = (float*)alloc((size_t)N * D * sizeof(float));
    float* xbuf   = (float*)alloc((size_t)N * D * sizeof(float));
    int*   colb   = (int*)alloc((size_t)E * sizeof(int));
    int*   cnt    = (int*)alloc((size_t)N * sizeof(int));
    int*   rowptr = (int*)alloc((size_t)(N + 1) * sizeof(int));
    int    NB     = (N + 255) / 256;
    int*   bsum   = (int*)alloc((size_t)NB * sizeof(int));
    int*   boff   = (int*)alloc((size_t)NB * sizeof(int));

    // CSR build (per call — inputs/ws are re-poisoned every timed launch)
    hipMemsetAsync(cnt, 0, (size_t)N * sizeof(int), stream);
    k_hist<<<(E + 255) / 256, 256, 0, stream>>>(dstv, cnt, E);
    k_blocksum<<<NB, 256, 0, stream>>>(cnt, bsum, N);
    k_scan_bsum<<<1, 256, 0, stream>>>(bsum, boff, NB);
    k_scan_write<<<NB, 256, 0, stream>>>(cnt, boff, rowptr, N, E);
    hipMemsetAsync(cnt, 0, (size_t)N * sizeof(int), stream);
    k_fill<<<(E + 255) / 256, 256, 0, stream>>>(src, dstv, rowptr, cnt, colb, E);

    float* out = (float*)d_out;
    const float* xin = features;
    for (int l = 0; l < L; l++) {
        k_gemm<<<(2 * N + 255) / 256, 256, 0, stream>>>(xin, W + (size_t)l * D * D, y, N);
        const float* basein = (l == 0) ? features : out;
        float bscale        = (l == 0) ? invlp1 : 1.f;
        k_spmm<<<(N + 3) / 4, 256, 0, stream>>>(y, rowptr, colb, basein, bscale, invlp1, xbuf, out, N);
        xin = xbuf;
    }
}